// Round 4
// baseline (174.602 us; speedup 1.0000x reference)
//
#include <hip/hip_runtime.h>
#include <cstdint>
#include <cstddef>

// Problem constants
#define BQ 8
#define CDIM 64
#define HQ 64
#define WQ 64
#define KDIM 512
#define N_SIG 32768   // B*H*W
#define S_NNZ 4

// d_out float offsets (outputs concatenated flat in return order)
#define DIFF_ENC_OFF 2097152
#define DIFF_DICT_OFF 2097153
#define IDS_OFF 2097154
#define NUM_STEPS_OFF 18874370
#define MEAN_D_OFF 18874371
#define MEAN_Z_OFF 18874372
#define NORM_Z_OFF 18874373
#define TOP_PCT_OFF 18874374
#define NUM_ZEROS_OFF 18874375

// ws float offsets
// [0..4)   : accs[2] doubles: sumAbsZ, sumSq   (zeroed by k_ga block 0)
// [4..9)   : hist[5] ints                      (zeroed by k_ga block 0)
// [16..24) : pd[8] per-block |Dn| partial sums
// [24..536): invn[512]
#define WS_PD 16
#define WS_INV 24
#define WS_DNT 536
#define WS_G 33304
#define WS_WG 295448   // float4 per signal (deduped gamma)
#define WS_WI 426520   // int4 per signal (idx)

typedef float v2f __attribute__((ext_vector_type(2)));

// ---- dictionary norms + normalized DnT (k-major): 8 blocks x 64 threads ----
__global__ __launch_bounds__(64) void k_dict(const float* __restrict__ D,
                                             float* __restrict__ DnT,
                                             float* __restrict__ invn,
                                             float* __restrict__ pd) {
  int tid = threadIdx.x;
  int k = blockIdx.x * 64 + tid;
  float ss = 0.f;
  for (int c = 0; c < CDIM; ++c) {
    float v = D[c * KDIM + k];
    ss = fmaf(v, v, ss);
  }
  float nrm = sqrtf(ss);
  invn[k] = 1.0f / nrm;
  float sabs = 0.f;
  for (int c = 0; c < CDIM; ++c) {
    float v = D[c * KDIM + k] / nrm;
    DnT[k * CDIM + c] = v;
    sabs += fabsf(v);
  }
#pragma unroll
  for (int off = 32; off >= 1; off >>= 1) sabs += __shfl_xor(sabs, off);
  if (tid == 0) pd[blockIdx.x] = sabs;
}

// ---- fused 128x128-tile GEMM:
//   blocks 0..15    : G = (D^T D) * invn_i * invn_j   (4x4 tiles of 128)
//   blocks 16..1039 : alpha0 = (X @ D) * invn_j       (256 m-tiles x 4 n-tiles)
__global__ __launch_bounds__(256) void k_ga(const float* __restrict__ X,
                                            const float* __restrict__ D,
                                            const float* __restrict__ invn,
                                            float* __restrict__ A0,
                                            float* __restrict__ G,
                                            float* __restrict__ W) {
  __shared__ float As[64 * 128];
  __shared__ float Bs[64 * 128];
  int tid = threadIdx.x;
  bool gram = blockIdx.x < 16;
  if (blockIdx.x == 0 && tid < 16) ((unsigned int*)W)[tid] = 0u;  // accs+hist zero

  int nb0, mt = 0, ti = 0;
  if (gram) {
    ti = (int)blockIdx.x >> 2;
    nb0 = ((int)blockIdx.x & 3) * 128;
  } else {
    int bb = (int)blockIdx.x - 16;
    mt = bb >> 2;            // 0..255 m-tile (128 signals each)
    nb0 = (bb & 3) * 128;
  }

  // ---- stage B tile (D columns nb0..nb0+127), c-major [c][128] ----
#pragma unroll
  for (int p = 0; p < 8; ++p) {
    int f = tid + p * 256;
    int c = f >> 5, c4 = (f & 31) * 4;
    float4 v = *(const float4*)&D[(size_t)c * KDIM + nb0 + c4];
    *(float4*)&Bs[c * 128 + c4] = v;
  }
  // ---- stage A tile ----
  if (gram) {
    int na0 = ti * 128;
#pragma unroll
    for (int p = 0; p < 8; ++p) {
      int f = tid + p * 256;
      int c = f >> 5, c4 = (f & 31) * 4;
      float4 v = *(const float4*)&D[(size_t)c * KDIM + na0 + c4];
      *(float4*)&As[c * 128 + c4] = v;
    }
  } else {
    int b = mt >> 5;
    int off = (mt & 31) * 128;  // within the 4096 (h*64+w) plane
#pragma unroll
    for (int p = 0; p < 8; ++p) {
      int f = tid + p * 256;
      int c = f >> 5, c4 = (f & 31) * 4;
      float4 v = *(const float4*)&X[((size_t)b * CDIM + c) * 4096 + off + c4];
      *(float4*)&As[c * 128 + c4] = v;
    }
  }
  __syncthreads();

  int mg = tid >> 4, ng = tid & 15;
  int m0 = mg * 8, n0 = ng * 8;
  v2f acc[8][4] = {};
#pragma unroll 2
  for (int c = 0; c < 64; ++c) {
    float4 a0v = *(const float4*)&As[c * 128 + m0];
    float4 a1v = *(const float4*)&As[c * 128 + m0 + 4];
    float4 b0v = *(const float4*)&Bs[c * 128 + n0];
    float4 b1v = *(const float4*)&Bs[c * 128 + n0 + 4];
    float aa[8] = {a0v.x, a0v.y, a0v.z, a0v.w, a1v.x, a1v.y, a1v.z, a1v.w};
    v2f bb[4] = {{b0v.x, b0v.y}, {b0v.z, b0v.w}, {b1v.x, b1v.y}, {b1v.z, b1v.w}};
#pragma unroll
    for (int i = 0; i < 8; ++i) {
      v2f ad = {aa[i], aa[i]};
#pragma unroll
      for (int j = 0; j < 4; ++j)
        acc[i][j] = __builtin_elementwise_fma(ad, bb[j], acc[i][j]);
    }
  }

  // ---- epilogue: scale + store ----
  float4 s0 = *(const float4*)&invn[nb0 + n0];
  float4 s1 = *(const float4*)&invn[nb0 + n0 + 4];
  float sn[8] = {s0.x, s0.y, s0.z, s0.w, s1.x, s1.y, s1.z, s1.w};
  if (gram) {
    int na0 = ti * 128;
    float4 t0 = *(const float4*)&invn[na0 + m0];
    float4 t1 = *(const float4*)&invn[na0 + m0 + 4];
    float sm[8] = {t0.x, t0.y, t0.z, t0.w, t1.x, t1.y, t1.z, t1.w};
#pragma unroll
    for (int i = 0; i < 8; ++i) {
      float r[8];
#pragma unroll
      for (int j = 0; j < 4; ++j) {
        r[2 * j] = acc[i][j].x * sm[i] * sn[2 * j];
        r[2 * j + 1] = acc[i][j].y * sm[i] * sn[2 * j + 1];
      }
      size_t row = (size_t)(na0 + m0 + i) * KDIM + nb0 + n0;
      *(float4*)&G[row] = make_float4(r[0], r[1], r[2], r[3]);
      *(float4*)&G[row + 4] = make_float4(r[4], r[5], r[6], r[7]);
    }
  } else {
#pragma unroll
    for (int i = 0; i < 8; ++i) {
      float r[8];
#pragma unroll
      for (int j = 0; j < 4; ++j) {
        r[2 * j] = acc[i][j].x * sn[2 * j];
        r[2 * j + 1] = acc[i][j].y * sn[2 * j + 1];
      }
      size_t row = (size_t)(mt * 128 + m0 + i) * KDIM + nb0 + n0;
      *(float4*)&A0[row] = make_float4(r[0], r[1], r[2], r[3]);
      *(float4*)&A0[row + 4] = make_float4(r[4], r[5], r[6], r[7]);
    }
  }
}

// ---- fp32 solve, no pivoting (G_II near-identity), saved reciprocals ----
template <int SZ>
__device__ __forceinline__ void solve_sz(const float (&gs)[4][4], const float (&rhs)[4],
                                         float (&gamma)[4]) {
  float M[SZ][SZ];
  float y[SZ];
  float idg[SZ];
#pragma unroll
  for (int a = 0; a < SZ; ++a) {
    y[a] = rhs[a];
#pragma unroll
    for (int b = 0; b < SZ; ++b) M[a][b] = gs[a][b] + (a == b ? 1e-7f : 0.0f);
  }
#pragma unroll
  for (int p = 0; p < SZ; ++p) {
    float ip = __builtin_amdgcn_rcpf(M[p][p]);
    idg[p] = ip;
#pragma unroll
    for (int r = p + 1; r < SZ; ++r) {
      float f = M[r][p] * ip;
#pragma unroll
      for (int c = p + 1; c < SZ; ++c) M[r][c] = fmaf(-f, M[p][c], M[r][c]);
      y[r] = fmaf(-f, y[p], y[r]);
    }
  }
#pragma unroll
  for (int r = SZ - 1; r >= 0; --r) {
    float t = y[r];
#pragma unroll
    for (int c = r + 1; c < SZ; ++c) t = fmaf(-M[r][c], gamma[c], t);
    gamma[r] = t * idg[r];
  }
}

template <int K>
__device__ __forceinline__ void omp_step(int lane, int n, const float* __restrict__ G,
                                         const float* __restrict__ A0,
                                         float (&a0)[8], float (&al)[8], float (&Grow)[3][8],
                                         float (&gs)[4][4], float (&rhs)[4], int (&idx)[4],
                                         float (&gamma)[4]) {
  // argmax |al| over 512, first-occurrence (lowest k) wins
  float mx = fabsf(al[0]);
#pragma unroll
  for (int m = 1; m < 8; ++m) mx = fmaxf(mx, fabsf(al[m]));
#pragma unroll
  for (int off = 32; off >= 1; off >>= 1) mx = fmaxf(mx, __shfl_xor(mx, off));
  int sk = 1 << 30;
#pragma unroll
  for (int m = 0; m < 8; ++m) {
    unsigned long long bm = __ballot(fabsf(al[m]) == mx);
    if (bm) {
      int kk = (int)__builtin_ctzll(bm) * 8 + m;
      sk = kk < sk ? kk : sk;
    }
  }
  idx[K] = sk;  // wave-uniform (derived from ballots)

  const float* grow_base = G + (size_t)sk * KDIM;
  if constexpr (K < 3) {
    const float4* gp = (const float4*)(grow_base + lane * 8);
    float4 r0 = gp[0], r1 = gp[1];
    Grow[K][0] = r0.x; Grow[K][1] = r0.y; Grow[K][2] = r0.z; Grow[K][3] = r0.w;
    Grow[K][4] = r1.x; Grow[K][5] = r1.y; Grow[K][6] = r1.z; Grow[K][7] = r1.w;
  }

#pragma unroll
  for (int b = 0; b < K; ++b) {
    float v = grow_base[idx[b]];
    gs[K][b] = v;
    gs[b][K] = v;
  }
  gs[K][K] = grow_base[sk];
  rhs[K] = A0[(size_t)n * KDIM + sk];

  solve_sz<K + 1>(gs, rhs, gamma);

  if constexpr (K < 3) {
#pragma unroll
    for (int m = 0; m < 8; ++m) {
      float acc = a0[m];
#pragma unroll
      for (int a = 0; a <= K; ++a) acc = fmaf(-gamma[a], Grow[a][m], acc);
      al[m] = acc;
    }
  }
}

// ---- OMP main: one wave per signal ----
__global__ __launch_bounds__(256) void k_omp(const float* __restrict__ A0,
                                             const float* __restrict__ G,
                                             float4* __restrict__ wg, int4* __restrict__ wi) {
  int tid = threadIdx.x;
  int lane = tid & 63;
  int wv = __builtin_amdgcn_readfirstlane(tid >> 6);
  int n = blockIdx.x * 4 + wv;  // grid = 8192 blocks
  const float4* ap = (const float4*)(A0 + (size_t)n * KDIM + lane * 8);
  float4 v0 = ap[0], v1 = ap[1];
  float a0[8] = {v0.x, v0.y, v0.z, v0.w, v1.x, v1.y, v1.z, v1.w};
  float al[8];
#pragma unroll
  for (int m = 0; m < 8; ++m) al[m] = a0[m];
  float Grow[3][8];
  float gs[4][4];
  float rhs[4];
  int idx[4];
  float gamma[4];
  omp_step<0>(lane, n, G, A0, a0, al, Grow, gs, rhs, idx, gamma);
  omp_step<1>(lane, n, G, A0, a0, al, Grow, gs, rhs, idx, gamma);
  omp_step<2>(lane, n, G, A0, a0, al, Grow, gs, rhs, idx, gamma);
  omp_step<3>(lane, n, G, A0, a0, al, Grow, gs, rhs, idx, gamma);
  // dedupe: scatter-set semantics — later slot with same index wins
  bool k0 = (idx[0] != idx[1]) && (idx[0] != idx[2]) && (idx[0] != idx[3]);
  bool k1 = (idx[1] != idx[2]) && (idx[1] != idx[3]);
  bool k2 = (idx[2] != idx[3]);
  if (lane == 0) {
    wg[n] = make_float4(k0 ? gamma[0] : 0.f, k1 ? gamma[1] : 0.f,
                        k2 ? gamma[2] : 0.f, gamma[3]);
    wi[n] = make_int4(idx[0], idx[1], idx[2], idx[3]);
  }
}

// ---- fused epilogue: blocks 0..511 quant+stats, blocks 512..2559 dense ids ----
__global__ __launch_bounds__(256) void k_ei(const float* __restrict__ X,
                                            const float* __restrict__ DnT,
                                            const float4* __restrict__ wg,
                                            const int4* __restrict__ wi,
                                            float* __restrict__ out, double* __restrict__ accs,
                                            int* __restrict__ hist) {
  __shared__ __align__(16) int sIdx[64][4];
  __shared__ __align__(16) float sKg[64][4];
  __shared__ float q[64 * 65];
  __shared__ float red[4];
  int tid = threadIdx.x;

  if (blockIdx.x < 512) {
    int bh = blockIdx.x;
    int b = bh >> 6, h = bh & 63;
    if (tid < 64) {
      int w = tid;
      int n = bh * 64 + w;
      int4 iv = wi[n];
      float4 gv = wg[n];  // already deduped in k_omp
      sIdx[w][0] = iv.x; sIdx[w][1] = iv.y; sIdx[w][2] = iv.z; sIdx[w][3] = iv.w;
      sKg[w][0] = gv.x; sKg[w][1] = gv.y; sKg[w][2] = gv.z; sKg[w][3] = gv.w;
      int nz = (int)(gv.x != 0.f) + (int)(gv.y != 0.f) +
               (int)(gv.z != 0.f) + (int)(gv.w != 0.f);
      float s = fabsf(gv.x) + fabsf(gv.y) + fabsf(gv.z) + fabsf(gv.w);
#pragma unroll
      for (int off = 32; off >= 1; off >>= 1) s += __shfl_xor(s, off);
#pragma unroll
      for (int v = 0; v < 5; ++v) {
        unsigned long long m = __ballot(nz == v);
        if (tid == 0) {
          int c = (int)__popcll(m);
          if (c) atomicAdd(&hist[v], c);
        }
      }
      if (tid == 0) atomicAdd(&accs[0], (double)s);
    }
    __syncthreads();

    int w2 = tid & 63, p = tid >> 6, c0 = p * 16;
    float acc[16] = {};
#pragma unroll
    for (int s = 0; s < 4; ++s) {
      int ks = sIdx[w2][s];
      float g = sKg[w2][s];
      const float4* dp = (const float4*)(DnT + (size_t)ks * CDIM + c0);
#pragma unroll
      for (int i4 = 0; i4 < 4; ++i4) {
        float4 d = dp[i4];
        acc[i4 * 4 + 0] = fmaf(g, d.x, acc[i4 * 4 + 0]);
        acc[i4 * 4 + 1] = fmaf(g, d.y, acc[i4 * 4 + 1]);
        acc[i4 * 4 + 2] = fmaf(g, d.z, acc[i4 * 4 + 2]);
        acc[i4 * 4 + 3] = fmaf(g, d.w, acc[i4 * 4 + 3]);
      }
    }
#pragma unroll
    for (int i = 0; i < 16; ++i) q[(c0 + i) * 65 + w2] = acc[i];
    __syncthreads();

    float sumsq = 0.f;
#pragma unroll
    for (int pass = 0; pass < 16; ++pass) {
      int c = pass * 4 + p;
      float qv = q[c * 65 + w2];
      size_t off = (((size_t)b * CDIM + c) * HQ + h) * WQ + w2;
      float xv = X[off];
      float d = qv - xv;
      sumsq = fmaf(d, d, sumsq);
      out[off] = qv;
    }

#pragma unroll
    for (int off = 32; off >= 1; off >>= 1) sumsq += __shfl_xor(sumsq, off);
    if ((tid & 63) == 0) red[tid >> 6] = sumsq;
    __syncthreads();
    if (tid == 0) atomicAdd(&accs[1], (double)(red[0] + red[1] + red[2] + red[3]));
  } else {
    // ---------------- dense ids write ----------------
    int bid = blockIdx.x - 512;
    int bh = bid >> 2, kq = bid & 3;
    int b = bh >> 6, h = bh & 63;
    if (tid < 64) {
      int n = bh * 64 + tid;
      *(int4*)&sIdx[tid][0] = wi[n];
      *(float4*)&sKg[tid][0] = wg[n];
    }
    __syncthreads();
    int w = tid & 63, kp = tid >> 6;
    int4 iv = *(int4*)&sIdx[w][0];
    float4 gv = *(float4*)&sKg[w][0];
    int k0 = kq * 128 + kp * 32;
    float* ids = out + IDS_OFF;
    size_t base = (((size_t)b * KDIM + k0) * HQ + h) * WQ + w;
#pragma unroll
    for (int kk = 0; kk < 32; ++kk) {
      int k = k0 + kk;
      float v = 0.f;
      v = (k == iv.x) ? gv.x : v;
      v = (k == iv.y) ? gv.y : v;
      v = (k == iv.z) ? gv.z : v;
      v = (k == iv.w) ? gv.w : v;
      ids[base + (size_t)kk * HQ * WQ] = v;
    }
  }
}

// ---- finalize scalars ----
__global__ __launch_bounds__(64) void k_final(const double* __restrict__ accs,
                                              const int* __restrict__ hist,
                                              const float* __restrict__ pd,
                                              float* __restrict__ out) {
  if (threadIdx.x == 0) {
    float sumAbsD = 0.f;
#pragma unroll
    for (int i = 0; i < 8; ++i) sumAbsD += pd[i];
    double sumAbsZ = accs[0], sumSq = accs[1];
    float diff = (float)(sumSq / 2097152.0);
    out[DIFF_ENC_OFF] = diff;
    out[DIFF_DICT_OFF] = diff;
    out[NUM_STEPS_OFF] = 4.0f;
    out[MEAN_D_OFF] = sumAbsD / 32768.0f;
    out[MEAN_Z_OFF] = (float)(sumAbsZ / 16777216.0);
    int h0 = hist[0], h1 = hist[1], h2 = hist[2], h3 = hist[3], h4 = hist[4];
    out[NORM_Z_OFF] = (float)((double)(h1 + 2 * h2 + 3 * h3 + 4 * h4) / 32768.0);
    int cum = 0, res = 0;
    for (int v = 4; v >= 0; --v) {
      cum += hist[v];
      if (cum >= 327) { res = v; break; }
    }
    out[TOP_PCT_OFF] = (float)res;
    out[NUM_ZEROS_OFF] = (float)h0;
  }
}

extern "C" void kernel_launch(void* const* d_in, const int* in_sizes, int n_in,
                              void* d_out, int out_size, void* d_ws, size_t ws_size,
                              hipStream_t stream) {
  (void)in_sizes; (void)n_in; (void)out_size; (void)ws_size;
  const float* X = (const float*)d_in[0];    // [8,64,64,64]
  const float* D = (const float*)d_in[1];    // [64,512]
  float* out = (float*)d_out;
  float* W = (float*)d_ws;
  double* accs = (double*)d_ws;
  int* hist = (int*)W + 4;
  float* pd = W + WS_PD;
  float* invn = W + WS_INV;
  float* DnT = W + WS_DNT;
  float* G = W + WS_G;
  float4* wgam = (float4*)(W + WS_WG);
  int4* widx = (int4*)(W + WS_WI);
  float* A0 = out;  // stage alpha0 in d_out[0 .. 16,777,216) — overwritten later

  hipLaunchKernelGGL(k_dict, dim3(8), dim3(64), 0, stream, D, DnT, invn, pd);
  hipLaunchKernelGGL(k_ga, dim3(1040), dim3(256), 0, stream, X, D, invn, A0, G, W);
  hipLaunchKernelGGL(k_omp, dim3(8192), dim3(256), 0, stream, A0, G, wgam, widx);
  hipLaunchKernelGGL(k_ei, dim3(2560), dim3(256), 0, stream, X, DnT, wgam, widx, out, accs, hist);
  hipLaunchKernelGGL(k_final, dim3(1), dim3(64), 0, stream, accs, hist, pd, out);
}